// Round 4
// baseline (7272.331 us; speedup 1.0000x reference)
//
#include <hip/hip_runtime.h>
#include <hip/hip_bf16.h>

#define B_  64
#define T_  2048
#define H_  128
#define G_  384      // 3*H
#define D0_ 18

typedef __hip_bfloat16 bf16;

__device__ __forceinline__ float sigmoidf_(float v) {
    return 1.0f / (1.0f + __expf(-v));
}
__device__ __forceinline__ float b2f(bf16 v) { return __bfloat162float(v); }
__device__ __forceinline__ unsigned short f2bu(float v) {
    bf16 b = __float2bfloat16(v);
    return *reinterpret_cast<unsigned short*>(&b);
}
// unpack two packed bf16 (little-endian pair in a u32) to floats
__device__ __forceinline__ float2 unpk(unsigned u) {
    float2 r;
    r.x = __uint_as_float(u << 16);
    r.y = __uint_as_float(u & 0xffff0000u);
    return r;
}

// ---------------------------------------------------------------------------
// Layer 0: fused input projection (D0=18) + recurrent scan. One WG per
// (batch, dir); 512 threads; thread (q=tid>>7, j=tid&127) holds W_hh rows
// {j,128+j,256+j}, K-slice [q*32,q*32+32) in fp32 registers. Output bf16.
// ---------------------------------------------------------------------------
__global__ __launch_bounds__(512, 1) void gru_l0(
    const float* __restrict__ x,
    const float* __restrict__ wih_f, const float* __restrict__ whh_f,
    const float* __restrict__ bih_f, const float* __restrict__ bhh_f,
    const float* __restrict__ wih_r, const float* __restrict__ whh_r,
    const float* __restrict__ bih_r, const float* __restrict__ bhh_r,
    bf16* __restrict__ l0_out)
{
    const int wg  = blockIdx.x;      // 0..127
    const int dir = wg & 1;
    const int b   = wg >> 1;
    const int tid = threadIdx.x;
    const int q   = tid >> 7;        // 0..3 (wave-uniform)
    const int j   = tid & 127;

    const float* Wih = dir ? wih_r : wih_f;
    const float* Whh = dir ? whh_r : whh_f;
    const float* Bih = dir ? bih_r : bih_f;
    const float* Bhh = dir ? bhh_r : bhh_f;

    __shared__ float h[H_];
    __shared__ float xb[32];                 // x_t (18 used)
    __shared__ float part[4][3][H_];
    __shared__ float wih_s[G_ * D0_];        // 27648 B
    __shared__ float crz[2][H_];
    __shared__ float bnx[H_], bnh[H_];

    float w[3][32];
    #pragma unroll
    for (int g = 0; g < 3; ++g) {
        const float* wp = Whh + (size_t)(g * H_ + j) * H_ + q * 32;
        #pragma unroll
        for (int i = 0; i < 32; ++i) w[g][i] = wp[i];
    }
    for (int idx = tid; idx < G_ * D0_; idx += 512) wih_s[idx] = Wih[idx];
    if (tid < H_) {
        crz[0][j] = Bih[j]      + Bhh[j];
        crz[1][j] = Bih[H_ + j] + Bhh[H_ + j];
        bnx[j]    = Bih[2*H_ + j];
        bnh[j]    = Bhh[2*H_ + j];
        h[j] = 0.0f;
    }
    __syncthreads();

    const float* xrow = x + (size_t)b * T_ * D0_;
    bf16* orow = l0_out + (size_t)b * T_ * (2 * H_) + dir * H_;

    for (int s = 0; s < T_; ++s) {
        const int t = dir ? (T_ - 1 - s) : s;

        if (tid < D0_) xb[tid] = xrow[(size_t)t * D0_ + tid];
        float ar = 0.f, az = 0.f, an = 0.f;
        const float* hp = &h[q * 32];
        #pragma unroll
        for (int i = 0; i < 32; ++i) {
            float hv = hp[i];
            ar = fmaf(w[0][i], hv, ar);
            az = fmaf(w[1][i], hv, az);
            an = fmaf(w[2][i], hv, an);
        }
        part[q][0][j] = ar; part[q][1][j] = az; part[q][2][j] = an;
        __syncthreads();

        if (tid < H_) {
            float hr = part[0][0][j] + part[1][0][j] + part[2][0][j] + part[3][0][j];
            float hz = part[0][1][j] + part[1][1][j] + part[2][1][j] + part[3][1][j];
            float hn = part[0][2][j] + part[1][2][j] + part[2][2][j] + part[3][2][j];
            float xr = crz[0][j], xz = crz[1][j], xn = bnx[j];
            #pragma unroll
            for (int i = 0; i < D0_; ++i) {
                float xv = xb[i];
                xr = fmaf(wih_s[(size_t)j * D0_ + i],          xv, xr);
                xz = fmaf(wih_s[(size_t)(H_ + j) * D0_ + i],   xv, xz);
                xn = fmaf(wih_s[(size_t)(2*H_ + j) * D0_ + i], xv, xn);
            }
            float r = sigmoidf_(xr + hr);
            float z = sigmoidf_(xz + hz);
            float n = tanhf(xn + r * (hn + bnh[j]));
            float hnew = (1.0f - z) * n + z * h[j];
            orow[(size_t)t * (2 * H_) + j] = __float2bfloat16(hnew);
            h[j] = hnew;
        }
        __syncthreads();
    }
}

// ---------------------------------------------------------------------------
// Single-direction xg GEMM over a batch chunk:
// C(rows x 384) = A(rows x 256, bf16)·W^T(fp32) + b. rows = nB*T, A offset by
// b_base. fp32 accum, 128x128 tile, BK=8, 256 threads, 8x8/thread. Out bf16.
// ---------------------------------------------------------------------------
__global__ __launch_bounds__(256, 2) void xg_gemm1(
    const bf16* __restrict__ A,       // already offset to chunk start
    const float* __restrict__ W, const float* __restrict__ bias,
    bf16* __restrict__ xg)            // chunk-local, rows x 384
{
    __shared__ float As[8][128];
    __shared__ float Bs[8][128];
    const int tid = threadIdx.x;
    const int m0 = blockIdx.x * 128;
    const int n0 = blockIdx.y * 128;   // 0,128,256
    const int tn = tid & 15, tm = tid >> 4;
    const int ar = tid >> 1;           // 0..127
    const int ac = (tid & 1) * 4;      // 0 or 4

    const float* wrow = W + (size_t)(n0 + ar) * 256;
    const bf16*  arow = A + (size_t)(m0 + ar) * 256;

    float acc[8][8];
    #pragma unroll
    for (int i = 0; i < 8; ++i)
        #pragma unroll
        for (int jj = 0; jj < 8; ++jj) acc[i][jj] = 0.f;

    for (int k0 = 0; k0 < 256; k0 += 8) {
        ushort4 au = *(const ushort4*)(arow + k0 + ac);
        float4  bv = *(const float4*)(wrow + k0 + ac);
        As[ac + 0][ar] = b2f(*reinterpret_cast<bf16*>(&au.x));
        As[ac + 1][ar] = b2f(*reinterpret_cast<bf16*>(&au.y));
        As[ac + 2][ar] = b2f(*reinterpret_cast<bf16*>(&au.z));
        As[ac + 3][ar] = b2f(*reinterpret_cast<bf16*>(&au.w));
        Bs[ac + 0][ar] = bv.x;
        Bs[ac + 1][ar] = bv.y;
        Bs[ac + 2][ar] = bv.z;
        Bs[ac + 3][ar] = bv.w;
        __syncthreads();
        #pragma unroll
        for (int kk = 0; kk < 8; ++kk) {
            float a[8], bb[8];
            #pragma unroll
            for (int i = 0; i < 8; ++i) a[i] = As[kk][tm * 8 + i];
            #pragma unroll
            for (int i = 0; i < 8; ++i) bb[i] = Bs[kk][tn * 8 + i];
            #pragma unroll
            for (int i = 0; i < 8; ++i)
                #pragma unroll
                for (int jj = 0; jj < 8; ++jj)
                    acc[i][jj] = fmaf(a[i], bb[jj], acc[i][jj]);
        }
        __syncthreads();
    }

    #pragma unroll
    for (int i = 0; i < 8; ++i) {
        const int m = m0 + tm * 8 + i;
        bf16* drow = xg + (size_t)m * G_ + n0 + tn * 8;
        #pragma unroll
        for (int jj = 0; jj < 8; ++jj)
            drow[jj] = __float2bfloat16(acc[i][jj] + bias[n0 + tn * 8 + jj]);
    }
}

// ---------------------------------------------------------------------------
// Layer 1, one direction over a batch chunk (nB WGs): scan over precomputed
// xg (chunk-local); FC fused: wave-reduce + atomicAdd into fp32 d_out
// (pre-seeded with fc_b).
// ---------------------------------------------------------------------------
__global__ __launch_bounds__(512, 1) void gru_l1_dir(
    const bf16* __restrict__ xg,      // chunk-local
    const float* __restrict__ whh, const float* __restrict__ bhh,
    const float* __restrict__ fc_w,
    float* __restrict__ out, int dir, int b_base)
{
    const int bl  = blockIdx.x;       // chunk-local batch
    const int b   = b_base + bl;
    const int tid = threadIdx.x;
    const int q   = tid >> 7;
    const int j   = tid & 127;

    __shared__ float h[H_];
    __shared__ float part[4][3][H_];
    __shared__ float bhh_s[3][H_];

    float w[3][32];
    #pragma unroll
    for (int g = 0; g < 3; ++g) {
        const float* wp = whh + (size_t)(g * H_ + j) * H_ + q * 32;
        #pragma unroll
        for (int i = 0; i < 32; ++i) w[g][i] = wp[i];
    }
    float f0 = 0.f, f1 = 0.f;
    if (tid < H_) {
        bhh_s[0][j] = bhh[j];
        bhh_s[1][j] = bhh[H_ + j];
        bhh_s[2][j] = bhh[2*H_ + j];
        h[j] = 0.0f;
        f0 = fc_w[dir * H_ + j];
        f1 = fc_w[2 * H_ + dir * H_ + j];
    }
    __syncthreads();

    const bf16* xgrow = xg + (size_t)bl * T_ * G_;
    float* obase = out + (size_t)b * T_ * 2;

    for (int s = 0; s < T_; ++s) {
        const int t = dir ? (T_ - 1 - s) : s;

        float xgr_v = 0.f, xgz_v = 0.f, xgn_v = 0.f;
        if (tid < H_) {
            const bf16* xp = xgrow + (size_t)t * G_;
            xgr_v = b2f(xp[j]);
            xgz_v = b2f(xp[H_ + j]);
            xgn_v = b2f(xp[2*H_ + j]);
        }

        float ar = 0.f, az = 0.f, an = 0.f;
        const float* hp = &h[q * 32];
        #pragma unroll
        for (int i = 0; i < 32; ++i) {
            float hv = hp[i];
            ar = fmaf(w[0][i], hv, ar);
            az = fmaf(w[1][i], hv, az);
            an = fmaf(w[2][i], hv, an);
        }
        part[q][0][j] = ar; part[q][1][j] = az; part[q][2][j] = an;
        __syncthreads();

        if (tid < H_) {
            float hr = part[0][0][j] + part[1][0][j] + part[2][0][j] + part[3][0][j];
            float hz = part[0][1][j] + part[1][1][j] + part[2][1][j] + part[3][1][j];
            float hn = part[0][2][j] + part[1][2][j] + part[2][2][j] + part[3][2][j];
            float r = sigmoidf_(xgr_v + hr + bhh_s[0][j]);
            float z = sigmoidf_(xgz_v + hz + bhh_s[1][j]);
            float n = tanhf(xgn_v + r * (hn + bhh_s[2][j]));
            float hnew = (1.0f - z) * n + z * h[j];
            h[j] = hnew;

            float s0 = f0 * hnew, s1 = f1 * hnew;
            #pragma unroll
            for (int off = 32; off >= 1; off >>= 1) {
                s0 += __shfl_xor(s0, off);
                s1 += __shfl_xor(s1, off);
            }
            if ((tid & 63) == 0) {
                atomicAdd(&obase[(size_t)t * 2 + 0], s0);
                atomicAdd(&obase[(size_t)t * 2 + 1], s1);
            }
        }
        __syncthreads();
    }
}

// ---------------------------------------------------------------------------
// Fallback layer 1: fully fused input projection (no xg buffer). fp32 weights
// packed to bf16 pairs in registers: W_ih 96 u32 + W_hh 48 u32 per thread.
// 128 WGs (b,dir), 512 threads. Keeps (W_hh·h)_n separate for the n-gate.
// ---------------------------------------------------------------------------
__global__ __launch_bounds__(512, 1) void gru_l1_fused(
    const bf16* __restrict__ l0_out,
    const float* __restrict__ wih_f, const float* __restrict__ whh_f,
    const float* __restrict__ bih_f, const float* __restrict__ bhh_f,
    const float* __restrict__ wih_r, const float* __restrict__ whh_r,
    const float* __restrict__ bih_r, const float* __restrict__ bhh_r,
    const float* __restrict__ fc_w,
    float* __restrict__ out)
{
    const int wg  = blockIdx.x;
    const int dir = wg & 1;
    const int b   = wg >> 1;
    const int tid = threadIdx.x;
    const int q   = tid >> 7;
    const int j   = tid & 127;

    const float* Wih = dir ? wih_r : wih_f;
    const float* Whh = dir ? whh_r : whh_f;
    const float* Bih = dir ? bih_r : bih_f;
    const float* Bhh = dir ? bhh_r : bhh_f;

    __shared__ float h[H_];
    __shared__ float xt[2][256];
    __shared__ float part[4][4][H_];   // r(x+h), z(x+h), n_x, n_h
    __shared__ float crz[2][H_];
    __shared__ float bnx[H_], bnh[H_];

    unsigned wih_p[3][32];   // rows {j,128+j,256+j}, cols [q*64, q*64+64)
    unsigned whh_p[3][16];   // cols [q*32, q*32+32)
    #pragma unroll
    for (int g = 0; g < 3; ++g) {
        const float* p1 = Wih + (size_t)(g * H_ + j) * 256 + q * 64;
        #pragma unroll
        for (int i = 0; i < 32; ++i)
            wih_p[g][i] = (unsigned)f2bu(p1[2*i]) | ((unsigned)f2bu(p1[2*i+1]) << 16);
        const float* p2 = Whh + (size_t)(g * H_ + j) * H_ + q * 32;
        #pragma unroll
        for (int i = 0; i < 16; ++i)
            whh_p[g][i] = (unsigned)f2bu(p2[2*i]) | ((unsigned)f2bu(p2[2*i+1]) << 16);
    }
    float f0 = 0.f, f1 = 0.f;
    if (tid < H_) {
        crz[0][j] = Bih[j]      + Bhh[j];
        crz[1][j] = Bih[H_ + j] + Bhh[H_ + j];
        bnx[j]    = Bih[2*H_ + j];
        bnh[j]    = Bhh[2*H_ + j];
        h[j] = 0.0f;
        f0 = fc_w[dir * H_ + j];
        f1 = fc_w[2 * H_ + dir * H_ + j];
    }
    const bf16* lrow = l0_out + (size_t)b * T_ * 256;
    float* obase = out + (size_t)b * T_ * 2;

    {
        const int t0 = dir ? (T_ - 1) : 0;
        if (tid < 256) xt[0][tid] = b2f(lrow[(size_t)t0 * 256 + tid]);
    }
    __syncthreads();

    for (int s = 0; s < T_; ++s) {
        const int t   = dir ? (T_ - 1 - s) : s;
        const int cur = s & 1;

        // prefetch next step's x into the other buffer (race-free: readers of
        // that buffer are 2 barriers away)
        if (s + 1 < T_ && tid < 256) {
            const int tn_ = dir ? (T_ - 2 - s) : (s + 1);
            xt[cur ^ 1][tid] = b2f(lrow[(size_t)tn_ * 256 + tid]);
        }

        float ar = 0.f, az = 0.f, anh = 0.f;
        const float* hp = &h[q * 32];
        #pragma unroll
        for (int i = 0; i < 16; ++i) {
            float2 hv; hv.x = hp[2*i]; hv.y = hp[2*i + 1];
            float2 w0 = unpk(whh_p[0][i]);
            float2 w1 = unpk(whh_p[1][i]);
            float2 w2 = unpk(whh_p[2][i]);
            ar  = fmaf(w0.x, hv.x, fmaf(w0.y, hv.y, ar));
            az  = fmaf(w1.x, hv.x, fmaf(w1.y, hv.y, az));
            anh = fmaf(w2.x, hv.x, fmaf(w2.y, hv.y, anh));
        }
        float xr = 0.f, xz = 0.f, xn = 0.f;
        const float* xp = &xt[cur][q * 64];
        #pragma unroll
        for (int i = 0; i < 32; ++i) {
            float2 xv; xv.x = xp[2*i]; xv.y = xp[2*i + 1];
            float2 w0 = unpk(wih_p[0][i]);
            float2 w1 = unpk(wih_p[1][i]);
            float2 w2 = unpk(wih_p[2][i]);
            xr = fmaf(w0.x, xv.x, fmaf(w0.y, xv.y, xr));
            xz = fmaf(w1.x, xv.x, fmaf(w1.y, xv.y, xz));
            xn = fmaf(w2.x, xv.x, fmaf(w2.y, xv.y, xn));
        }
        part[q][0][j] = ar + xr;
        part[q][1][j] = az + xz;
        part[q][2][j] = xn;
        part[q][3][j] = anh;
        __syncthreads();

        if (tid < H_) {
            float pr  = part[0][0][j] + part[1][0][j] + part[2][0][j] + part[3][0][j];
            float pz  = part[0][1][j] + part[1][1][j] + part[2][1][j] + part[3][1][j];
            float pxn = part[0][2][j] + part[1][2][j] + part[2][2][j] + part[3][2][j];
            float phn = part[0][3][j] + part[1][3][j] + part[2][3][j] + part[3][3][j];
            float r = sigmoidf_(pr + crz[0][j]);
            float z = sigmoidf_(pz + crz[1][j]);
            float n = tanhf(pxn + bnx[j] + r * (phn + bnh[j]));
            float hnew = (1.0f - z) * n + z * h[j];
            h[j] = hnew;

            float s0 = f0 * hnew, s1 = f1 * hnew;
            #pragma unroll
            for (int off = 32; off >= 1; off >>= 1) {
                s0 += __shfl_xor(s0, off);
                s1 += __shfl_xor(s1, off);
            }
            if ((tid & 63) == 0) {
                atomicAdd(&obase[(size_t)t * 2 + 0], s0);
                atomicAdd(&obase[(size_t)t * 2 + 1], s1);
            }
        }
        __syncthreads();
    }
}

__global__ __launch_bounds__(256) void init_out(float* __restrict__ out,
                                                const float* __restrict__ fcb)
{
    const int i = blockIdx.x * 256 + threadIdx.x;   // B*T*2 total
    out[i] = fcb[i & 1];
}

extern "C" void kernel_launch(void* const* d_in, const int* in_sizes, int n_in,
                              void* d_out, int out_size, void* d_ws, size_t ws_size,
                              hipStream_t stream)
{
    if (n_in < 19) return;
    const float* x     = (const float*)d_in[0];
    const float* wih0  = (const float*)d_in[1];
    const float* whh0  = (const float*)d_in[2];
    const float* bih0  = (const float*)d_in[3];
    const float* bhh0  = (const float*)d_in[4];
    const float* wih0r = (const float*)d_in[5];
    const float* whh0r = (const float*)d_in[6];
    const float* bih0r = (const float*)d_in[7];
    const float* bhh0r = (const float*)d_in[8];
    const float* wih1  = (const float*)d_in[9];
    const float* whh1  = (const float*)d_in[10];
    const float* bih1  = (const float*)d_in[11];
    const float* bhh1  = (const float*)d_in[12];
    const float* wih1r = (const float*)d_in[13];
    const float* whh1r = (const float*)d_in[14];
    const float* bih1r = (const float*)d_in[15];
    const float* bhh1r = (const float*)d_in[16];
    const float* fcw   = (const float*)d_in[17];
    const float* fcb   = (const float*)d_in[18];
    float* out = (float*)d_out;

    const size_t nBT  = (size_t)B_ * T_;                 // 131072
    const size_t l0_b = nBT * 2 * H_ * sizeof(bf16);     // 64 MiB
    const size_t xg_full = nBT * G_ * sizeof(bf16);      // 96 MiB (one dir, all B)
    const size_t xg_half = xg_full / 2;                  // 48 MiB

    char* p = (char*)d_ws;
    bf16* l0o = (bf16*)p;  p += l0_b;

    const int nOut = B_ * T_ * 2;              // 262144

    if (ws_size < l0_b) return;                // nothing correct possible

    gru_l0<<<dim3(2 * B_), dim3(512), 0, stream>>>(
        x, wih0, whh0, bih0, bhh0, wih0r, whh0r, bih0r, bhh0r, l0o);
    init_out<<<dim3(nOut / 256), dim3(256), 0, stream>>>(out, fcb);

    if (ws_size >= l0_b + xg_full) {
        bf16* xg = (bf16*)p;
        // fwd
        xg_gemm1<<<dim3(1024, 3), dim3(256), 0, stream>>>(l0o, wih1, bih1, xg);
        gru_l1_dir<<<dim3(B_), dim3(512), 0, stream>>>(xg, whh1, bhh1, fcw, out, 0, 0);
        // bwd (reuses xg; stream-ordered)
        xg_gemm1<<<dim3(1024, 3), dim3(256), 0, stream>>>(l0o, wih1r, bih1r, xg);
        gru_l1_dir<<<dim3(B_), dim3(512), 0, stream>>>(xg, whh1r, bhh1r, fcw, out, 1, 0);
    } else if (ws_size >= l0_b + xg_half) {
        bf16* xg = (bf16*)p;
        const size_t rows = nBT / 2;           // 32 batches
        for (int dir = 0; dir < 2; ++dir) {
            const float* W  = dir ? wih1r : wih1;
            const float* Bi = dir ? bih1r : bih1;
            const float* Wh = dir ? whh1r : whh1;
            const float* Bh = dir ? bhh1r : bhh1;
            for (int c = 0; c < 2; ++c) {
                const bf16* Achunk = l0o + (size_t)c * rows * 256;
                xg_gemm1<<<dim3(512, 3), dim3(256), 0, stream>>>(Achunk, W, Bi, xg);
                gru_l1_dir<<<dim3(B_ / 2), dim3(512), 0, stream>>>(
                    xg, Wh, Bh, fcw, out, dir, c * (B_ / 2));
            }
        }
    } else {
        gru_l1_fused<<<dim3(2 * B_), dim3(512), 0, stream>>>(
            l0o, wih1, whh1, bih1, bhh1, wih1r, whh1r, bih1r, bhh1r, fcw, out);
    }
}

// Round 5
// 5235.124 us; speedup vs baseline: 1.3891x; 1.3891x over previous
//
#include <hip/hip_runtime.h>
#include <hip/hip_bf16.h>

#define B_  64
#define T_  2048
#define H_  128
#define G_  384      // 3*H
#define D0_ 18
#define WIN 16       // time-window for LDS staging / batched flush

typedef __hip_bfloat16 bf16;

__device__ __forceinline__ float sigmoidf_(float v) {
    return 1.0f / (1.0f + __expf(-v));
}
__device__ __forceinline__ float b2f(bf16 v) { return __bfloat162float(v); }

// ---------------------------------------------------------------------------
// Layer 0: fused input projection (D0=18) + recurrent scan.
// 128 WGs (b,dir) x 256 threads. Thread (q=tid>>7, j=tid&127) holds W_hh rows
// {j,128+j,256+j}, K-slice [q*64,q*64+64) in fp32 registers.
// x staged per 16-step window into LDS; h-history stashed in LDS and flushed
// as coalesced 16B stores once per window (keeps VMEM off the step path).
// ---------------------------------------------------------------------------
__global__ __launch_bounds__(256, 1) void gru_l0(
    const float* __restrict__ x,
    const float* __restrict__ wih_f, const float* __restrict__ whh_f,
    const float* __restrict__ bih_f, const float* __restrict__ bhh_f,
    const float* __restrict__ wih_r, const float* __restrict__ whh_r,
    const float* __restrict__ bih_r, const float* __restrict__ bhh_r,
    bf16* __restrict__ l0_out)
{
    const int wg  = blockIdx.x;      // 0..127
    const int dir = wg & 1;
    const int b   = wg >> 1;
    const int tid = threadIdx.x;
    const int q   = tid >> 7;        // 0..1 (wave-uniform)
    const int j   = tid & 127;

    const float* Wih = dir ? wih_r : wih_f;
    const float* Whh = dir ? whh_r : whh_f;
    const float* Bih = dir ? bih_r : bih_f;
    const float* Bhh = dir ? bhh_r : bhh_f;

    __shared__ float h[H_];
    __shared__ float xw[WIN][D0_];           // staged x window
    __shared__ float part[2][3][H_];
    __shared__ float wih_s[G_ * D0_];        // 27648 B
    __shared__ float crz[2][H_];
    __shared__ float bnx[H_], bnh[H_];
    __shared__ bf16  hst[WIN][H_];           // h history stash (4 KiB)

    float w[3][64];
    #pragma unroll
    for (int g = 0; g < 3; ++g) {
        const float* wp = Whh + (size_t)(g * H_ + j) * H_ + q * 64;
        #pragma unroll
        for (int i = 0; i < 64; ++i) w[g][i] = wp[i];
    }
    for (int idx = tid; idx < G_ * D0_; idx += 256) wih_s[idx] = Wih[idx];
    if (tid < H_) {
        crz[0][j] = Bih[j]      + Bhh[j];
        crz[1][j] = Bih[H_ + j] + Bhh[H_ + j];
        bnx[j]    = Bih[2*H_ + j];
        bnh[j]    = Bhh[2*H_ + j];
        h[j] = 0.0f;
    }
    __syncthreads();

    const float* xrow = x + (size_t)b * T_ * D0_;

    for (int wnd = 0; wnd < T_ / WIN; ++wnd) {
        // ---- stage x window (one vm drain per window) ----
        for (int idx = tid; idx < WIN * D0_; idx += 256) {
            const int si = idx / D0_, c = idx - si * D0_;
            const int s  = wnd * WIN + si;
            const int t  = dir ? (T_ - 1 - s) : s;
            xw[si][c] = xrow[(size_t)t * D0_ + c];
        }
        __syncthreads();

        for (int si = 0; si < WIN; ++si) {
            // phase A: partial recurrent dots
            float ar = 0.f, az = 0.f, an = 0.f;
            const float* hp = &h[q * 64];
            #pragma unroll
            for (int i = 0; i < 64; ++i) {
                const float hv = hp[i];
                ar = fmaf(w[0][i], hv, ar);
                az = fmaf(w[1][i], hv, az);
                an = fmaf(w[2][i], hv, an);
            }
            part[q][0][j] = ar; part[q][1][j] = az; part[q][2][j] = an;
            __syncthreads();

            // phase B: reduce + input proj + gates + h update
            if (tid < H_) {
                float hr = part[0][0][j] + part[1][0][j];
                float hz = part[0][1][j] + part[1][1][j];
                float hn = part[0][2][j] + part[1][2][j];
                float xr = crz[0][j], xz = crz[1][j], xn = bnx[j];
                #pragma unroll
                for (int i = 0; i < D0_; ++i) {
                    const float xv = xw[si][i];
                    xr = fmaf(wih_s[(size_t)j * D0_ + i],          xv, xr);
                    xz = fmaf(wih_s[(size_t)(H_ + j) * D0_ + i],   xv, xz);
                    xn = fmaf(wih_s[(size_t)(2*H_ + j) * D0_ + i], xv, xn);
                }
                const float r = sigmoidf_(xr + hr);
                const float z = sigmoidf_(xz + hz);
                const float n = tanhf(xn + r * (hn + bnh[j]));
                const float hnew = (1.0f - z) * n + z * h[j];
                hst[si][j] = __float2bfloat16(hnew);
                h[j] = hnew;
            }
            __syncthreads();
        }

        // ---- flush h history: 16 t x 128 bf16, coalesced uint4 stores ----
        {
            const int toff = tid >> 4, grp = tid & 15;
            const int s = wnd * WIN + toff;
            const int t = dir ? (T_ - 1 - s) : s;
            const uint4 v = *(const uint4*)&hst[toff][grp * 8];
            *(uint4*)(l0_out + ((size_t)b * T_ + t) * (2 * H_) + dir * H_ + grp * 8) = v;
        }
        // next stage's __syncthreads() orders hst reuse; stores drain there.
    }
}

// ---------------------------------------------------------------------------
// Single-direction xg GEMM: C(131072 x 384) = l0_out(131072 x 256, bf16)·W^T
// (fp32) + b. fp32 accum, 128x128 tile, BK=8, 256 threads, 8x8/thr. Out bf16.
// ---------------------------------------------------------------------------
__global__ __launch_bounds__(256, 2) void xg_gemm1(
    const bf16* __restrict__ A,
    const float* __restrict__ W, const float* __restrict__ bias,
    bf16* __restrict__ xg)
{
    __shared__ float As[8][128];
    __shared__ float Bs[8][128];
    const int tid = threadIdx.x;
    const int m0 = blockIdx.x * 128;
    const int n0 = blockIdx.y * 128;   // 0,128,256
    const int tn = tid & 15, tm = tid >> 4;
    const int ar = tid >> 1;           // 0..127
    const int ac = (tid & 1) * 4;      // 0 or 4

    const float* wrow = W + (size_t)(n0 + ar) * 256;
    const bf16*  arow = A + (size_t)(m0 + ar) * 256;

    float acc[8][8];
    #pragma unroll
    for (int i = 0; i < 8; ++i)
        #pragma unroll
        for (int jj = 0; jj < 8; ++jj) acc[i][jj] = 0.f;

    for (int k0 = 0; k0 < 256; k0 += 8) {
        ushort4 au = *(const ushort4*)(arow + k0 + ac);
        float4  bv = *(const float4*)(wrow + k0 + ac);
        As[ac + 0][ar] = b2f(*reinterpret_cast<bf16*>(&au.x));
        As[ac + 1][ar] = b2f(*reinterpret_cast<bf16*>(&au.y));
        As[ac + 2][ar] = b2f(*reinterpret_cast<bf16*>(&au.z));
        As[ac + 3][ar] = b2f(*reinterpret_cast<bf16*>(&au.w));
        Bs[ac + 0][ar] = bv.x;
        Bs[ac + 1][ar] = bv.y;
        Bs[ac + 2][ar] = bv.z;
        Bs[ac + 3][ar] = bv.w;
        __syncthreads();
        #pragma unroll
        for (int kk = 0; kk < 8; ++kk) {
            float a[8], bb[8];
            #pragma unroll
            for (int i = 0; i < 8; ++i) a[i] = As[kk][tm * 8 + i];
            #pragma unroll
            for (int i = 0; i < 8; ++i) bb[i] = Bs[kk][tn * 8 + i];
            #pragma unroll
            for (int i = 0; i < 8; ++i)
                #pragma unroll
                for (int jj = 0; jj < 8; ++jj)
                    acc[i][jj] = fmaf(a[i], bb[jj], acc[i][jj]);
        }
        __syncthreads();
    }

    #pragma unroll
    for (int i = 0; i < 8; ++i) {
        const int m = m0 + tm * 8 + i;
        bf16* drow = xg + (size_t)m * G_ + n0 + tn * 8;
        #pragma unroll
        for (int jj = 0; jj < 8; ++jj)
            drow[jj] = __float2bfloat16(acc[i][jj] + bias[n0 + tn * 8 + jj]);
    }
}

// ---------------------------------------------------------------------------
// Layer 1 scan + fused FC. 256 threads/WG, one (b,dir) stream per WG.
// mode 0: dir=0, out = fc_b + val (store);  mode 1: dir=1, out += val (RMW);
// mode 2: 128 WGs, dir=blk&1, atomicAdd flush (out pre-seeded with fc_b).
// xg staged per 16-step window into LDS; FC results stashed and flushed per
// window (no per-step global traffic).
// ---------------------------------------------------------------------------
__global__ __launch_bounds__(256, 1) void gru_l1(
    const bf16* __restrict__ xg_f, const bf16* __restrict__ xg_r,
    const float* __restrict__ whh_f, const float* __restrict__ bhh_f,
    const float* __restrict__ whh_r, const float* __restrict__ bhh_r,
    const float* __restrict__ fc_w, const float* __restrict__ fc_b,
    float* __restrict__ out, int mode)
{
    int dir, b;
    if (mode == 2) { dir = blockIdx.x & 1; b = blockIdx.x >> 1; }
    else           { dir = mode;           b = blockIdx.x; }
    const int tid = threadIdx.x;
    const int q   = tid >> 7;
    const int j   = tid & 127;

    const bf16*  xg  = dir ? xg_r : xg_f;
    const float* Whh = dir ? whh_r : whh_f;
    const float* Bhh = dir ? bhh_r : bhh_f;

    __shared__ float h[H_];
    __shared__ float part[2][3][H_];
    __shared__ float bhh_s[3][H_];
    __shared__ bf16  xgw[WIN * G_];          // 12 KiB staged xg window
    __shared__ float stash[2][WIN][2];       // FC partials per wave

    float w[3][64];
    #pragma unroll
    for (int g = 0; g < 3; ++g) {
        const float* wp = Whh + (size_t)(g * H_ + j) * H_ + q * 64;
        #pragma unroll
        for (int i = 0; i < 64; ++i) w[g][i] = wp[i];
    }
    float f0 = 0.f, f1 = 0.f;
    if (tid < H_) {
        bhh_s[0][j] = Bhh[j];
        bhh_s[1][j] = Bhh[H_ + j];
        bhh_s[2][j] = Bhh[2*H_ + j];
        h[j] = 0.0f;
        f0 = fc_w[dir * H_ + j];
        f1 = fc_w[2 * H_ + dir * H_ + j];
    }
    __syncthreads();

    const bf16* xgb = xg + (size_t)b * T_ * G_;

    for (int wnd = 0; wnd < T_ / WIN; ++wnd) {
        // ---- stage xg window: contiguous t-range, ascending-t layout ----
        const size_t tlo = dir ? (size_t)(T_ - (wnd + 1) * WIN) : (size_t)wnd * WIN;
        const bf16* src = xgb + tlo * G_;
        #pragma unroll
        for (int r = 0; r < 3; ++r) {
            const int e = (r * 256 + tid) * 8;   // 6144 bf16 total
            *(uint4*)&xgw[e] = *(const uint4*)(src + e);
        }
        __syncthreads();

        for (int si = 0; si < WIN; ++si) {
            float ar = 0.f, az = 0.f, an = 0.f;
            const float* hp = &h[q * 64];
            #pragma unroll
            for (int i = 0; i < 64; ++i) {
                const float hv = hp[i];
                ar = fmaf(w[0][i], hv, ar);
                az = fmaf(w[1][i], hv, az);
                an = fmaf(w[2][i], hv, an);
            }
            part[q][0][j] = ar; part[q][1][j] = az; part[q][2][j] = an;
            __syncthreads();

            if (tid < H_) {
                const int row = dir ? (WIN - 1 - si) : si;
                const bf16* xp = &xgw[row * G_];
                const float xgr_v = b2f(xp[j]);
                const float xgz_v = b2f(xp[H_ + j]);
                const float xgn_v = b2f(xp[2*H_ + j]);

                const float hr = part[0][0][j] + part[1][0][j];
                const float hz = part[0][1][j] + part[1][1][j];
                const float hn = part[0][2][j] + part[1][2][j];
                const float r = sigmoidf_(xgr_v + hr + bhh_s[0][j]);
                const float z = sigmoidf_(xgz_v + hz + bhh_s[1][j]);
                const float n = tanhf(xgn_v + r * (hn + bhh_s[2][j]));
                const float hnew = (1.0f - z) * n + z * h[j];
                h[j] = hnew;

                float s0 = f0 * hnew, s1 = f1 * hnew;
                #pragma unroll
                for (int off = 32; off >= 1; off >>= 1) {
                    s0 += __shfl_xor(s0, off);
                    s1 += __shfl_xor(s1, off);
                }
                if ((tid & 63) == 0) {
                    stash[tid >> 6][si][0] = s0;
                    stash[tid >> 6][si][1] = s1;
                }
            }
            __syncthreads();
        }

        // ---- flush FC results for this window ----
        if (tid < 2 * WIN) {
            const int si = tid >> 1, c = tid & 1;
            const int s = wnd * WIN + si;
            const int t = dir ? (T_ - 1 - s) : s;
            const float v = stash[0][si][c] + stash[1][si][c];
            float* dst = out + ((size_t)b * T_ + t) * 2 + c;
            if (mode == 0)      *dst = fc_b[c] + v;
            else if (mode == 1) *dst = *dst + v;
            else                atomicAdd(dst, v);
        }
        // next stage's __syncthreads() orders stash reuse + drains stores.
    }
}

__global__ __launch_bounds__(256) void init_out(float* __restrict__ out,
                                                const float* __restrict__ fcb)
{
    const int i = blockIdx.x * 256 + threadIdx.x;   // B*T*2 total
    out[i] = fcb[i & 1];
}

extern "C" void kernel_launch(void* const* d_in, const int* in_sizes, int n_in,
                              void* d_out, int out_size, void* d_ws, size_t ws_size,
                              hipStream_t stream)
{
    if (n_in < 19) return;
    const float* x     = (const float*)d_in[0];
    const float* wih0  = (const float*)d_in[1];
    const float* whh0  = (const float*)d_in[2];
    const float* bih0  = (const float*)d_in[3];
    const float* bhh0  = (const float*)d_in[4];
    const float* wih0r = (const float*)d_in[5];
    const float* whh0r = (const float*)d_in[6];
    const float* bih0r = (const float*)d_in[7];
    const float* bhh0r = (const float*)d_in[8];
    const float* wih1  = (const float*)d_in[9];
    const float* whh1  = (const float*)d_in[10];
    const float* bih1  = (const float*)d_in[11];
    const float* bhh1  = (const float*)d_in[12];
    const float* wih1r = (const float*)d_in[13];
    const float* whh1r = (const float*)d_in[14];
    const float* bih1r = (const float*)d_in[15];
    const float* bhh1r = (const float*)d_in[16];
    const float* fcw   = (const float*)d_in[17];
    const float* fcb   = (const float*)d_in[18];
    float* out = (float*)d_out;

    const size_t nBT  = (size_t)B_ * T_;                 // 131072
    const size_t l0_b = nBT * 2 * H_ * sizeof(bf16);     // 64 MiB
    const size_t xg_b = nBT * G_ * sizeof(bf16);         // 96 MiB per dir
    const size_t xg_el = nBT * G_;

    if (ws_size < l0_b + xg_b) return;         // below known-working floor

    bf16* l0o = (bf16*)d_ws;
    bf16* xgf = (bf16*)((char*)d_ws + l0_b);

    gru_l0<<<dim3(2 * B_), dim3(256), 0, stream>>>(
        x, wih0, whh0, bih0, bhh0, wih0r, whh0r, bih0r, bhh0r, l0o);

    if (ws_size >= l0_b + 2 * xg_b) {
        // merged path: both directions in one l1 dispatch
        bf16* xgr = xgf + xg_el;
        init_out<<<dim3((B_ * T_ * 2) / 256), dim3(256), 0, stream>>>(out, fcb);
        xg_gemm1<<<dim3(1024, 3), dim3(256), 0, stream>>>(l0o, wih1,  bih1,  xgf);
        xg_gemm1<<<dim3(1024, 3), dim3(256), 0, stream>>>(l0o, wih1r, bih1r, xgr);
        gru_l1<<<dim3(2 * B_), dim3(256), 0, stream>>>(
            xgf, xgr, whh1, bhh1, whh1r, bhh1r, fcw, fcb, out, 2);
    } else {
        // sequential path: fwd (store), then bwd (RMW add), reusing xgf
        xg_gemm1<<<dim3(1024, 3), dim3(256), 0, stream>>>(l0o, wih1, bih1, xgf);
        gru_l1<<<dim3(B_), dim3(256), 0, stream>>>(
            xgf, xgf, whh1, bhh1, whh1r, bhh1r, fcw, fcb, out, 0);
        xg_gemm1<<<dim3(1024, 3), dim3(256), 0, stream>>>(l0o, wih1r, bih1r, xgf);
        gru_l1<<<dim3(B_), dim3(256), 0, stream>>>(
            xgf, xgf, whh1, bhh1, whh1r, bhh1r, fcw, fcb, out, 1);
    }
}

// Round 6
// 4146.218 us; speedup vs baseline: 1.7540x; 1.2626x over previous
//
#include <hip/hip_runtime.h>
#include <hip/hip_bf16.h>

#define B_  64
#define T_  2048
#define H_  128
#define G_  384      // 3*H
#define D0_ 18
#define WIN 16

typedef __hip_bfloat16 bf16;
typedef __attribute__((ext_vector_type(4))) float f32x4;
typedef __attribute__((ext_vector_type(8))) short s16x8;

__device__ __forceinline__ float b2f(bf16 v) { return __bfloat162float(v); }
__device__ __forceinline__ float sigf(float v) { return 1.0f / (1.0f + __expf(-v)); }
// tanh via exp: 1 - 2/(e^{2x}+1); saturates correctly at +-inf
__device__ __forceinline__ float tanhf_(float v) {
    return 1.0f - 2.0f / (__expf(2.0f * v) + 1.0f);
}

// ---------------------------------------------------------------------------
// Layer 0 scan. 128 WGs (b,dir) x 256 threads. Thread (j=tid>>1, half=tid&1)
// holds W_hh rows {j,128+j,256+j} K-slice [half*64,+64) and W_ih K-slice
// [half*9,+9) in registers. One barrier/step; pair-reduce via shfl_xor(1);
// h double-buffered in LDS; h history flushed per 16-step window.
// ---------------------------------------------------------------------------
__global__ __launch_bounds__(256, 1) void gru_l0(
    const float* __restrict__ x,
    const float* __restrict__ wih_f, const float* __restrict__ whh_f,
    const float* __restrict__ bih_f, const float* __restrict__ bhh_f,
    const float* __restrict__ wih_r, const float* __restrict__ whh_r,
    const float* __restrict__ bih_r, const float* __restrict__ bhh_r,
    bf16* __restrict__ l0_out)
{
    const int wg   = blockIdx.x;
    const int dir  = wg & 1;
    const int b    = wg >> 1;
    const int tid  = threadIdx.x;
    const int j    = tid >> 1;
    const int half = tid & 1;

    const float* Wih = dir ? wih_r : wih_f;
    const float* Whh = dir ? whh_r : whh_f;
    const float* Bih = dir ? bih_r : bih_f;
    const float* Bhh = dir ? bhh_r : bhh_f;

    __shared__ float h[2][H_];
    __shared__ float xw[WIN][D0_];
    __shared__ bf16  hst[WIN][H_];

    // W_hh slices -> registers (float4)
    float4 wr4[16], wz4[16], wn4[16];
    {
        const float* rr = Whh + (size_t)j * H_ + half * 64;
        const float* rz = Whh + (size_t)(H_ + j) * H_ + half * 64;
        const float* rn = Whh + (size_t)(2 * H_ + j) * H_ + half * 64;
        #pragma unroll
        for (int i = 0; i < 16; ++i) {
            wr4[i] = *(const float4*)(rr + 4 * i);
            wz4[i] = *(const float4*)(rz + 4 * i);
            wn4[i] = *(const float4*)(rn + 4 * i);
        }
    }
    // W_ih slices (9 each)
    float wxr[9], wxz[9], wxn[9];
    {
        const float* rr = Wih + (size_t)j * D0_ + half * 9;
        const float* rz = Wih + (size_t)(H_ + j) * D0_ + half * 9;
        const float* rn = Wih + (size_t)(2 * H_ + j) * D0_ + half * 9;
        #pragma unroll
        for (int i = 0; i < 9; ++i) { wxr[i] = rr[i]; wxz[i] = rz[i]; wxn[i] = rn[i]; }
    }
    const float crz0 = Bih[j]        + Bhh[j];
    const float crz1 = Bih[H_ + j]   + Bhh[H_ + j];
    const float bnx  = Bih[2*H_ + j];
    const float bnh  = Bhh[2*H_ + j];

    float h_j = 0.0f;
    if (half == 0) { h[0][j] = 0.0f; }
    __syncthreads();

    const float* xrow = x + (size_t)b * T_ * D0_;
    int cur = 0;

    for (int wnd = 0; wnd < T_ / WIN; ++wnd) {
        for (int idx = tid; idx < WIN * D0_; idx += 256) {
            const int si = idx / D0_, c = idx - si * D0_;
            const int s  = wnd * WIN + si;
            const int t  = dir ? (T_ - 1 - s) : s;
            xw[si][c] = xrow[(size_t)t * D0_ + c];
        }
        __syncthreads();

        for (int si = 0; si < WIN; ++si) {
            // recurrent partial dots over this thread's K-half
            const float4* hp = (const float4*)&h[cur][half * 64];
            float ar0 = 0.f, az0 = 0.f, an0 = 0.f;
            float ar1 = 0.f, az1 = 0.f, an1 = 0.f;
            #pragma unroll
            for (int i = 0; i < 16; i += 2) {
                const float4 h0 = hp[i], h1 = hp[i + 1];
                ar0 = fmaf(wr4[i].x, h0.x, ar0); ar0 = fmaf(wr4[i].y, h0.y, ar0);
                ar0 = fmaf(wr4[i].z, h0.z, ar0); ar0 = fmaf(wr4[i].w, h0.w, ar0);
                az0 = fmaf(wz4[i].x, h0.x, az0); az0 = fmaf(wz4[i].y, h0.y, az0);
                az0 = fmaf(wz4[i].z, h0.z, az0); az0 = fmaf(wz4[i].w, h0.w, az0);
                an0 = fmaf(wn4[i].x, h0.x, an0); an0 = fmaf(wn4[i].y, h0.y, an0);
                an0 = fmaf(wn4[i].z, h0.z, an0); an0 = fmaf(wn4[i].w, h0.w, an0);
                ar1 = fmaf(wr4[i+1].x, h1.x, ar1); ar1 = fmaf(wr4[i+1].y, h1.y, ar1);
                ar1 = fmaf(wr4[i+1].z, h1.z, ar1); ar1 = fmaf(wr4[i+1].w, h1.w, ar1);
                az1 = fmaf(wz4[i+1].x, h1.x, az1); az1 = fmaf(wz4[i+1].y, h1.y, az1);
                az1 = fmaf(wz4[i+1].z, h1.z, az1); az1 = fmaf(wz4[i+1].w, h1.w, az1);
                an1 = fmaf(wn4[i+1].x, h1.x, an1); an1 = fmaf(wn4[i+1].y, h1.y, an1);
                an1 = fmaf(wn4[i+1].z, h1.z, an1); an1 = fmaf(wn4[i+1].w, h1.w, an1);
            }
            // input projection partials
            float xr = 0.f, xz = 0.f, xn = 0.f;
            const float* xp = &xw[si][half * 9];
            #pragma unroll
            for (int i = 0; i < 9; ++i) {
                const float xv = xp[i];
                xr = fmaf(wxr[i], xv, xr);
                xz = fmaf(wxz[i], xv, xz);
                xn = fmaf(wxn[i], xv, xn);
            }
            float sr = ar0 + ar1 + xr;          // r gate (h + x parts combine)
            float sz = az0 + az1 + xz;          // z gate
            float sh = an0 + an1;               // n gate, h part (keep separate)
            // pair reduce (lane^1)
            sr += __shfl_xor(sr, 1);
            sz += __shfl_xor(sz, 1);
            sh += __shfl_xor(sh, 1);
            xn += __shfl_xor(xn, 1);

            const float r = sigf(sr + crz0);
            const float z = sigf(sz + crz1);
            const float n = tanhf_(xn + bnx + r * (sh + bnh));
            const float hnew = n + z * (h_j - n);
            h_j = hnew;
            if (half == 0) h[cur ^ 1][j] = hnew;
            else           hst[si][j] = __float2bfloat16(hnew);
            cur ^= 1;
            __syncthreads();
        }

        // flush 16 steps of h history (coalesced 16B stores)
        {
            const int toff = tid >> 4, grp = tid & 15;
            const int s = wnd * WIN + toff;
            const int t = dir ? (T_ - 1 - s) : s;
            const uint4 v = *(const uint4*)&hst[toff][grp * 8];
            *(uint4*)(l0_out + ((size_t)b * T_ + t) * (2 * H_) + dir * H_ + grp * 8) = v;
        }
        __syncthreads();
    }
}

// ---------------------------------------------------------------------------
// MFMA xg GEMM: C(131072 x 384) = A(131072 x 256, bf16) . W^T(384x256 fp32) +b
// Grid (1024, 3). 256 thr = 4 waves; wave covers 32 rows x 128 cols.
// LDS tiles padded to 40 shorts/row (2-way banks). Out bf16.
// ---------------------------------------------------------------------------
__global__ __launch_bounds__(256, 2) void xg_gemm_mfma(
    const bf16* __restrict__ A,
    const float* __restrict__ W, const float* __restrict__ bias,
    bf16* __restrict__ xg)
{
    __shared__ short As[128 * 40];
    __shared__ short Ws[128 * 40];
    __shared__ float Bias_s[128];

    const int tid  = threadIdx.x;
    const int lane = tid & 63;
    const int wv   = tid >> 6;
    const int m0   = blockIdx.x * 128;
    const int n0   = blockIdx.y * 128;

    if (tid < 128) Bias_s[tid] = bias[n0 + tid];

    f32x4 acc[2][8];
    #pragma unroll
    for (int mt = 0; mt < 2; ++mt)
        #pragma unroll
        for (int nt = 0; nt < 8; ++nt) acc[mt][nt] = (f32x4){0.f, 0.f, 0.f, 0.f};

    for (int k0 = 0; k0 < 256; k0 += 32) {
        // stage A tile: 128 rows x 32 k (bf16)
        #pragma unroll
        for (int i = 0; i < 2; ++i) {
            const int c = tid + i * 256;            // 512 uint4 chunks
            const int row = c >> 2, quad = c & 3;
            *(uint4*)&As[row * 40 + quad * 8] =
                *(const uint4*)(A + (size_t)(m0 + row) * 256 + k0 + quad * 8);
        }
        // stage W tile: 128 rows x 32 k, fp32 -> bf16
        #pragma unroll
        for (int i = 0; i < 4; ++i) {
            const int c = tid + i * 256;            // 1024 float4 chunks
            const int row = c >> 3, q = c & 7;
            const float4 v = *(const float4*)(W + (size_t)(n0 + row) * 256 + k0 + q * 4);
            ushort4 u;
            bf16 b0 = __float2bfloat16(v.x), b1 = __float2bfloat16(v.y);
            bf16 b2 = __float2bfloat16(v.z), b3 = __float2bfloat16(v.w);
            u.x = *(unsigned short*)&b0; u.y = *(unsigned short*)&b1;
            u.z = *(unsigned short*)&b2; u.w = *(unsigned short*)&b3;
            *(ushort4*)&Ws[row * 40 + q * 4] = u;
        }
        __syncthreads();

        s16x8 afr[2], bfr[8];
        #pragma unroll
        for (int mt = 0; mt < 2; ++mt)
            afr[mt] = *(const s16x8*)&As[(wv * 32 + mt * 16 + (lane & 15)) * 40 + (lane >> 4) * 8];
        #pragma unroll
        for (int nt = 0; nt < 8; ++nt)
            bfr[nt] = *(const s16x8*)&Ws[(nt * 16 + (lane & 15)) * 40 + (lane >> 4) * 8];

        #pragma unroll
        for (int mt = 0; mt < 2; ++mt)
            #pragma unroll
            for (int nt = 0; nt < 8; ++nt)
                acc[mt][nt] = __builtin_amdgcn_mfma_f32_16x16x32_bf16(
                    afr[mt], bfr[nt], acc[mt][nt], 0, 0, 0);
        __syncthreads();
    }

    // epilogue: C layout col = lane&15, row = (lane>>4)*4 + r   [m89-verified]
    #pragma unroll
    for (int mt = 0; mt < 2; ++mt) {
        #pragma unroll
        for (int nt = 0; nt < 8; ++nt) {
            const int n_l = nt * 16 + (lane & 15);
            const float bv = Bias_s[n_l];
            #pragma unroll
            for (int r = 0; r < 4; ++r) {
                const int m_g = m0 + wv * 32 + mt * 16 + (lane >> 4) * 4 + r;
                xg[(size_t)m_g * G_ + n0 + n_l] = __float2bfloat16(acc[mt][nt][r] + bv);
            }
        }
    }
}

// ---------------------------------------------------------------------------
// Layer 1 scan + fused FC. 256 thr; same lane-pair structure as gru_l0.
// mode 0: dir=0, out = fc_b + v (store); mode 1: dir=1, out += v (RMW);
// mode 2: 128 WGs (b,dir), atomicAdd (out pre-seeded with fc_b).
// ---------------------------------------------------------------------------
__global__ __launch_bounds__(256, 1) void gru_l1(
    const bf16* __restrict__ xg_f, const bf16* __restrict__ xg_r,
    const float* __restrict__ whh_f, const float* __restrict__ bhh_f,
    const float* __restrict__ whh_r, const float* __restrict__ bhh_r,
    const float* __restrict__ fc_w, const float* __restrict__ fc_b,
    float* __restrict__ out, int mode)
{
    int dir, b;
    if (mode == 2) { dir = blockIdx.x & 1; b = blockIdx.x >> 1; }
    else           { dir = mode;           b = blockIdx.x; }
    const int tid  = threadIdx.x;
    const int j    = tid >> 1;
    const int half = tid & 1;
    const int wid  = tid >> 6;

    const bf16*  xg  = dir ? xg_r : xg_f;
    const float* Whh = dir ? whh_r : whh_f;
    const float* Bhh = dir ? bhh_r : bhh_f;

    __shared__ float h[2][H_];
    __shared__ bf16  xgw[WIN * G_];          // 12 KiB window
    __shared__ float stash[4][WIN][2];

    float4 wr4[16], wz4[16], wn4[16];
    {
        const float* rr = Whh + (size_t)j * H_ + half * 64;
        const float* rz = Whh + (size_t)(H_ + j) * H_ + half * 64;
        const float* rn = Whh + (size_t)(2 * H_ + j) * H_ + half * 64;
        #pragma unroll
        for (int i = 0; i < 16; ++i) {
            wr4[i] = *(const float4*)(rr + 4 * i);
            wz4[i] = *(const float4*)(rz + 4 * i);
            wn4[i] = *(const float4*)(rn + 4 * i);
        }
    }
    const float cr  = Bhh[j];
    const float cz  = Bhh[H_ + j];
    const float cnh = Bhh[2*H_ + j];
    const float f0  = fc_w[dir * H_ + j];
    const float f1  = fc_w[2 * H_ + dir * H_ + j];

    float h_j = 0.0f;
    if (half == 0) h[0][j] = 0.0f;
    __syncthreads();

    const bf16* xgb = xg + (size_t)b * T_ * G_;
    int cur = 0;

    for (int wnd = 0; wnd < T_ / WIN; ++wnd) {
        const size_t tlo = dir ? (size_t)(T_ - (wnd + 1) * WIN) : (size_t)wnd * WIN;
        const bf16* src = xgb + tlo * G_;
        #pragma unroll
        for (int rr = 0; rr < 3; ++rr) {
            const int e = (rr * 256 + tid) * 8;   // 6144 bf16
            *(uint4*)&xgw[e] = *(const uint4*)(src + e);
        }
        __syncthreads();

        for (int si = 0; si < WIN; ++si) {
            const int row = dir ? (WIN - 1 - si) : si;
            const float xgr_v = b2f(xgw[row * G_ + j]);
            const float xgz_v = b2f(xgw[row * G_ + H_ + j]);
            const float xgn_v = b2f(xgw[row * G_ + 2 * H_ + j]);

            const float4* hp = (const float4*)&h[cur][half * 64];
            float ar0 = 0.f, az0 = 0.f, an0 = 0.f;
            float ar1 = 0.f, az1 = 0.f, an1 = 0.f;
            #pragma unroll
            for (int i = 0; i < 16; i += 2) {
                const float4 h0 = hp[i], h1 = hp[i + 1];
                ar0 = fmaf(wr4[i].x, h0.x, ar0); ar0 = fmaf(wr4[i].y, h0.y, ar0);
                ar0 = fmaf(wr4[i].z, h0.z, ar0); ar0 = fmaf(wr4[i].w, h0.w, ar0);
                az0 = fmaf(wz4[i].x, h0.x, az0); az0 = fmaf(wz4[i].y, h0.y, az0);
                az0 = fmaf(wz4[i].z, h0.z, az0); az0 = fmaf(wz4[i].w, h0.w, az0);
                an0 = fmaf(wn4[i].x, h0.x, an0); an0 = fmaf(wn4[i].y, h0.y, an0);
                an0 = fmaf(wn4[i].z, h0.z, an0); an0 = fmaf(wn4[i].w, h0.w, an0);
                ar1 = fmaf(wr4[i+1].x, h1.x, ar1); ar1 = fmaf(wr4[i+1].y, h1.y, ar1);
                ar1 = fmaf(wr4[i+1].z, h1.z, ar1); ar1 = fmaf(wr4[i+1].w, h1.w, ar1);
                az1 = fmaf(wz4[i+1].x, h1.x, az1); az1 = fmaf(wz4[i+1].y, h1.y, az1);
                az1 = fmaf(wz4[i+1].z, h1.z, az1); az1 = fmaf(wz4[i+1].w, h1.w, az1);
                an1 = fmaf(wn4[i+1].x, h1.x, an1); an1 = fmaf(wn4[i+1].y, h1.y, an1);
                an1 = fmaf(wn4[i+1].z, h1.z, an1); an1 = fmaf(wn4[i+1].w, h1.w, an1);
            }
            float sr = ar0 + ar1;
            float sz = az0 + az1;
            float sh = an0 + an1;
            sr += __shfl_xor(sr, 1);
            sz += __shfl_xor(sz, 1);
            sh += __shfl_xor(sh, 1);

            const float r = sigf(xgr_v + sr + cr);
            const float z = sigf(xgz_v + sz + cz);
            const float n = tanhf_(xgn_v + r * (sh + cnh));
            const float hnew = n + z * (h_j - n);
            h_j = hnew;
            if (half == 0) h[cur ^ 1][j] = hnew;
            cur ^= 1;

            // fused FC: sum f*hnew over j (half==0 contributes; wave reduce)
            float s0 = (half == 0) ? f0 * hnew : 0.f;
            float s1 = (half == 0) ? f1 * hnew : 0.f;
            #pragma unroll
            for (int off = 32; off >= 1; off >>= 1) {
                s0 += __shfl_xor(s0, off);
                s1 += __shfl_xor(s1, off);
            }
            if ((tid & 63) == 0) { stash[wid][si][0] = s0; stash[wid][si][1] = s1; }
            __syncthreads();
        }

        if (tid < 2 * WIN) {
            const int si = tid >> 1, c = tid & 1;
            const int s = wnd * WIN + si;
            const int t = dir ? (T_ - 1 - s) : s;
            const float v = stash[0][si][c] + stash[1][si][c]
                          + stash[2][si][c] + stash[3][si][c];
            float* dst = out + ((size_t)b * T_ + t) * 2 + c;
            if (mode == 0)      *dst = fc_b[c] + v;
            else if (mode == 1) *dst = *dst + v;
            else                atomicAdd(dst, v);
        }
        __syncthreads();
    }
}

__global__ __launch_bounds__(256) void init_out(float* __restrict__ out,
                                                const float* __restrict__ fcb)
{
    const int i = blockIdx.x * 256 + threadIdx.x;
    out[i] = fcb[i & 1];
}

extern "C" void kernel_launch(void* const* d_in, const int* in_sizes, int n_in,
                              void* d_out, int out_size, void* d_ws, size_t ws_size,
                              hipStream_t stream)
{
    if (n_in < 19) return;
    const float* x     = (const float*)d_in[0];
    const float* wih0  = (const float*)d_in[1];
    const float* whh0  = (const float*)d_in[2];
    const float* bih0  = (const float*)d_in[3];
    const float* bhh0  = (const float*)d_in[4];
    const float* wih0r = (const float*)d_in[5];
    const float* whh0r = (const float*)d_in[6];
    const float* bih0r = (const float*)d_in[7];
    const float* bhh0r = (const float*)d_in[8];
    const float* wih1  = (const float*)d_in[9];
    const float* whh1  = (const float*)d_in[10];
    const float* bih1  = (const float*)d_in[11];
    const float* bhh1  = (const float*)d_in[12];
    const float* wih1r = (const float*)d_in[13];
    const float* whh1r = (const float*)d_in[14];
    const float* bih1r = (const float*)d_in[15];
    const float* bhh1r = (const float*)d_in[16];
    const float* fcw   = (const float*)d_in[17];
    const float* fcb   = (const float*)d_in[18];
    float* out = (float*)d_out;

    const size_t nBT  = (size_t)B_ * T_;
    const size_t l0_b = nBT * 2 * H_ * sizeof(bf16);     // 64 MiB
    const size_t xg_b = nBT * G_ * sizeof(bf16);         // 96 MiB per dir
    const size_t xg_el = nBT * G_;

    if (ws_size < l0_b + xg_b) return;

    bf16* l0o = (bf16*)d_ws;
    bf16* xgf = (bf16*)((char*)d_ws + l0_b);

    gru_l0<<<dim3(2 * B_), dim3(256), 0, stream>>>(
        x, wih0, whh0, bih0, bhh0, wih0r, whh0r, bih0r, bhh0r, l0o);

    if (ws_size >= l0_b + 2 * xg_b) {
        bf16* xgr = xgf + xg_el;
        init_out<<<dim3((B_ * T_ * 2) / 256), dim3(256), 0, stream>>>(out, fcb);
        xg_gemm_mfma<<<dim3(1024, 3), dim3(256), 0, stream>>>(l0o, wih1,  bih1,  xgf);
        xg_gemm_mfma<<<dim3(1024, 3), dim3(256), 0, stream>>>(l0o, wih1r, bih1r, xgr);
        gru_l1<<<dim3(2 * B_), dim3(256), 0, stream>>>(
            xgf, xgr, whh1, bhh1, whh1r, bhh1r, fcw, fcb, out, 2);
    } else {
        xg_gemm_mfma<<<dim3(1024, 3), dim3(256), 0, stream>>>(l0o, wih1, bih1, xgf);
        gru_l1<<<dim3(B_), dim3(256), 0, stream>>>(
            xgf, xgf, whh1, bhh1, whh1r, bhh1r, fcw, fcb, out, 0);
        xg_gemm_mfma<<<dim3(1024, 3), dim3(256), 0, stream>>>(l0o, wih1r, bih1r, xgf);
        gru_l1<<<dim3(B_), dim3(256), 0, stream>>>(
            xgf, xgf, whh1, bhh1, whh1r, bhh1r, fcw, fcb, out, 1);
    }
}

// Round 7
// 4046.237 us; speedup vs baseline: 1.7973x; 1.0247x over previous
//
#include <hip/hip_runtime.h>
#include <hip/hip_bf16.h>

#define B_  64
#define T_  2048
#define H_  128
#define G_  384      // 3*H
#define D0_ 18
#define WIN 16

typedef __hip_bfloat16 bf16;
typedef __attribute__((ext_vector_type(4))) float f32x4;
typedef __attribute__((ext_vector_type(8))) short s16x8;

__device__ __forceinline__ float b2f(bf16 v) { return __bfloat162float(v); }
__device__ __forceinline__ float sigf(float v) { return 1.0f / (1.0f + __expf(-v)); }
__device__ __forceinline__ float tanhf_(float v) {
    return 1.0f - 2.0f / (__expf(2.0f * v) + 1.0f);
}

// h replica geometry: 4 replicas, stride 136 floats (phase 8 banks/replica).
// Replica kq is read at word kq*168 (=kq*136 + kq*32): the 4 kq groups hit
// disjoint bank quads {0,8,16,24}+4i -> conflict-free b128 reads.
#define HREP 136

// ---------------------------------------------------------------------------
// Layer 0 scan. 128 WGs (b,dir) x 512 threads (8 waves = 2/SIMD).
// Thread (kq=tid&3, j=tid>>2) holds W_hh rows {j,128+j,256+j} K-slice
// [kq*32,+32) in regs; kq<2 also hold W_ih K-slice [kq*9,+9).
// One barrier/step; 2-level shfl reduce; h in 4 bank-phased LDS replicas.
// ---------------------------------------------------------------------------
__global__ __launch_bounds__(512, 2) void gru_l0(
    const float* __restrict__ x,
    const float* __restrict__ wih_f, const float* __restrict__ whh_f,
    const float* __restrict__ bih_f, const float* __restrict__ bhh_f,
    const float* __restrict__ wih_r, const float* __restrict__ whh_r,
    const float* __restrict__ bih_r, const float* __restrict__ bhh_r,
    bf16* __restrict__ l0_out)
{
    const int wg  = blockIdx.x;
    const int dir = wg & 1;
    const int b   = wg >> 1;
    const int tid = threadIdx.x;
    const int kq  = tid & 3;
    const int j   = tid >> 2;

    const float* Wih = dir ? wih_r : wih_f;
    const float* Whh = dir ? whh_r : whh_f;
    const float* Bih = dir ? bih_r : bih_f;
    const float* Bhh = dir ? bhh_r : bhh_f;

    __shared__ float hrep[2][4 * HREP];
    __shared__ float xw[WIN][D0_];
    __shared__ bf16  hst[WIN][H_];

    float4 wr4[8], wz4[8], wn4[8];
    {
        const float* rr = Whh + (size_t)j * H_ + kq * 32;
        const float* rz = Whh + (size_t)(H_ + j) * H_ + kq * 32;
        const float* rn = Whh + (size_t)(2 * H_ + j) * H_ + kq * 32;
        #pragma unroll
        for (int i = 0; i < 8; ++i) {
            wr4[i] = *(const float4*)(rr + 4 * i);
            wz4[i] = *(const float4*)(rz + 4 * i);
            wn4[i] = *(const float4*)(rn + 4 * i);
        }
    }
    float wxr[9], wxz[9], wxn[9];
    if (kq < 2) {
        const float* rr = Wih + (size_t)j * D0_ + kq * 9;
        const float* rz = Wih + (size_t)(H_ + j) * D0_ + kq * 9;
        const float* rn = Wih + (size_t)(2 * H_ + j) * D0_ + kq * 9;
        #pragma unroll
        for (int i = 0; i < 9; ++i) { wxr[i] = rr[i]; wxz[i] = rz[i]; wxn[i] = rn[i]; }
    }
    const float crz0 = Bih[j]        + Bhh[j];
    const float crz1 = Bih[H_ + j]   + Bhh[H_ + j];
    const float bnx  = Bih[2*H_ + j];
    const float bnh  = Bhh[2*H_ + j];

    float h_j = 0.0f;
    hrep[0][kq * HREP + j] = 0.0f;

    const float* xrow = x + (size_t)b * T_ * D0_;

    // stage window 0
    for (int idx = tid; idx < WIN * D0_; idx += 512) {
        const int si = idx / D0_, c = idx - si * D0_;
        const int t  = dir ? (T_ - 1 - si) : si;
        xw[si][c] = xrow[(size_t)t * D0_ + c];
    }
    __syncthreads();

    int cur = 0;
    for (int wnd = 0; wnd < T_ / WIN; ++wnd) {
        for (int si = 0; si < WIN; ++si) {
            const float* hp = &hrep[cur][kq * 168];
            float4 hv[8];
            #pragma unroll
            for (int i = 0; i < 8; ++i) hv[i] = *(const float4*)(hp + 4 * i);

            float ar = 0.f, az = 0.f, an = 0.f;
            #pragma unroll
            for (int i = 0; i < 8; ++i) {
                const float4 h0 = hv[i];
                ar = fmaf(wr4[i].x, h0.x, ar); ar = fmaf(wr4[i].y, h0.y, ar);
                ar = fmaf(wr4[i].z, h0.z, ar); ar = fmaf(wr4[i].w, h0.w, ar);
                az = fmaf(wz4[i].x, h0.x, az); az = fmaf(wz4[i].y, h0.y, az);
                az = fmaf(wz4[i].z, h0.z, az); az = fmaf(wz4[i].w, h0.w, az);
                an = fmaf(wn4[i].x, h0.x, an); an = fmaf(wn4[i].y, h0.y, an);
                an = fmaf(wn4[i].z, h0.z, an); an = fmaf(wn4[i].w, h0.w, an);
            }
            float xr = 0.f, xz = 0.f, xn = 0.f;
            if (kq < 2) {
                const float* xp = &xw[si][kq * 9];
                #pragma unroll
                for (int i = 0; i < 9; ++i) {
                    const float xv = xp[i];
                    xr = fmaf(wxr[i], xv, xr);
                    xz = fmaf(wxz[i], xv, xz);
                    xn = fmaf(wxn[i], xv, xn);
                }
            }
            float sr = ar + xr, sz = az + xz, sh = an;
            sr += __shfl_xor(sr, 1); sr += __shfl_xor(sr, 2);
            sz += __shfl_xor(sz, 1); sz += __shfl_xor(sz, 2);
            sh += __shfl_xor(sh, 1); sh += __shfl_xor(sh, 2);
            xn += __shfl_xor(xn, 1); xn += __shfl_xor(xn, 2);

            const float r = sigf(sr + crz0);
            const float z = sigf(sz + crz1);
            const float n = tanhf_(xn + bnx + r * (sh + bnh));
            const float hnew = n + z * (h_j - n);
            h_j = hnew;
            hrep[cur ^ 1][kq * HREP + j] = hnew;
            if (kq == 2) hst[si][j] = __float2bfloat16(hnew);
            cur ^= 1;
            __syncthreads();
        }

        // flush this window's h history + stage next window's x
        if (tid < 256) {
            const int toff = tid >> 4, grp = tid & 15;
            const int s = wnd * WIN + toff;
            const int t = dir ? (T_ - 1 - s) : s;
            const uint4 v = *(const uint4*)&hst[toff][grp * 8];
            *(uint4*)(l0_out + ((size_t)b * T_ + t) * (2 * H_) + dir * H_ + grp * 8) = v;
        }
        if (wnd + 1 < T_ / WIN) {
            for (int idx = tid; idx < WIN * D0_; idx += 512) {
                const int si = idx / D0_, c = idx - si * D0_;
                const int s  = (wnd + 1) * WIN + si;
                const int t  = dir ? (T_ - 1 - s) : s;
                xw[si][c] = xrow[(size_t)t * D0_ + c];
            }
        }
        __syncthreads();
    }
}

// ---------------------------------------------------------------------------
// MFMA xg GEMM: C(131072 x 384) = A(131072 x 256, bf16) . W^T(384x256 fp32) +b
// Grid (1024, 3). 256 thr = 4 waves; wave covers 32 rows x 128 cols.
// ---------------------------------------------------------------------------
__global__ __launch_bounds__(256, 2) void xg_gemm_mfma(
    const bf16* __restrict__ A,
    const float* __restrict__ W, const float* __restrict__ bias,
    bf16* __restrict__ xg)
{
    __shared__ short As[128 * 40];
    __shared__ short Ws[128 * 40];
    __shared__ float Bias_s[128];

    const int tid  = threadIdx.x;
    const int lane = tid & 63;
    const int wv   = tid >> 6;
    const int m0   = blockIdx.x * 128;
    const int n0   = blockIdx.y * 128;

    if (tid < 128) Bias_s[tid] = bias[n0 + tid];

    f32x4 acc[2][8];
    #pragma unroll
    for (int mt = 0; mt < 2; ++mt)
        #pragma unroll
        for (int nt = 0; nt < 8; ++nt) acc[mt][nt] = (f32x4){0.f, 0.f, 0.f, 0.f};

    for (int k0 = 0; k0 < 256; k0 += 32) {
        #pragma unroll
        for (int i = 0; i < 2; ++i) {
            const int c = tid + i * 256;
            const int row = c >> 2, quad = c & 3;
            *(uint4*)&As[row * 40 + quad * 8] =
                *(const uint4*)(A + (size_t)(m0 + row) * 256 + k0 + quad * 8);
        }
        #pragma unroll
        for (int i = 0; i < 4; ++i) {
            const int c = tid + i * 256;
            const int row = c >> 3, q = c & 7;
            const float4 v = *(const float4*)(W + (size_t)(n0 + row) * 256 + k0 + q * 4);
            ushort4 u;
            bf16 b0 = __float2bfloat16(v.x), b1 = __float2bfloat16(v.y);
            bf16 b2 = __float2bfloat16(v.z), b3 = __float2bfloat16(v.w);
            u.x = *(unsigned short*)&b0; u.y = *(unsigned short*)&b1;
            u.z = *(unsigned short*)&b2; u.w = *(unsigned short*)&b3;
            *(ushort4*)&Ws[row * 40 + q * 4] = u;
        }
        __syncthreads();

        s16x8 afr[2], bfr[8];
        #pragma unroll
        for (int mt = 0; mt < 2; ++mt)
            afr[mt] = *(const s16x8*)&As[(wv * 32 + mt * 16 + (lane & 15)) * 40 + (lane >> 4) * 8];
        #pragma unroll
        for (int nt = 0; nt < 8; ++nt)
            bfr[nt] = *(const s16x8*)&Ws[(nt * 16 + (lane & 15)) * 40 + (lane >> 4) * 8];

        #pragma unroll
        for (int mt = 0; mt < 2; ++mt)
            #pragma unroll
            for (int nt = 0; nt < 8; ++nt)
                acc[mt][nt] = __builtin_amdgcn_mfma_f32_16x16x32_bf16(
                    afr[mt], bfr[nt], acc[mt][nt], 0, 0, 0);
        __syncthreads();
    }

    #pragma unroll
    for (int mt = 0; mt < 2; ++mt) {
        #pragma unroll
        for (int nt = 0; nt < 8; ++nt) {
            const int n_l = nt * 16 + (lane & 15);
            const float bv = Bias_s[n_l];
            #pragma unroll
            for (int r = 0; r < 4; ++r) {
                const int m_g = m0 + wv * 32 + mt * 16 + (lane >> 4) * 4 + r;
                xg[(size_t)m_g * G_ + n0 + n_l] = __float2bfloat16(acc[mt][nt][r] + bv);
            }
        }
    }
}

// ---------------------------------------------------------------------------
// Layer 1 scan + fused FC. 512 threads, kq=4 split, deferred FC reduce.
// mode 0: dir=0, out = fc_b + v; mode 1: dir=1, out += v; mode 2: 128 WGs,
// atomicAdd (out pre-seeded with fc_b).
// ---------------------------------------------------------------------------
__global__ __launch_bounds__(512, 2) void gru_l1(
    const bf16* __restrict__ xg_f, const bf16* __restrict__ xg_r,
    const float* __restrict__ whh_f, const float* __restrict__ bhh_f,
    const float* __restrict__ whh_r, const float* __restrict__ bhh_r,
    const float* __restrict__ fc_w, const float* __restrict__ fc_b,
    float* __restrict__ out, int mode)
{
    int dir, b;
    if (mode == 2) { dir = blockIdx.x & 1; b = blockIdx.x >> 1; }
    else           { dir = mode;           b = blockIdx.x; }
    const int tid = threadIdx.x;
    const int kq  = tid & 3;
    const int j   = tid >> 2;
    const int wid = tid >> 6;

    const bf16*  xg  = dir ? xg_r : xg_f;
    const float* Whh = dir ? whh_r : whh_f;
    const float* Bhh = dir ? bhh_r : bhh_f;

    __shared__ float hrep[2][4 * HREP];
    __shared__ bf16  xgw[WIN * G_];
    __shared__ float stash[8][WIN][2];

    float4 wr4[8], wz4[8], wn4[8];
    {
        const float* rr = Whh + (size_t)j * H_ + kq * 32;
        const float* rz = Whh + (size_t)(H_ + j) * H_ + kq * 32;
        const float* rn = Whh + (size_t)(2 * H_ + j) * H_ + kq * 32;
        #pragma unroll
        for (int i = 0; i < 8; ++i) {
            wr4[i] = *(const float4*)(rr + 4 * i);
            wz4[i] = *(const float4*)(rz + 4 * i);
            wn4[i] = *(const float4*)(rn + 4 * i);
        }
    }
    const float cr  = Bhh[j];
    const float cz  = Bhh[H_ + j];
    const float cnh = Bhh[2*H_ + j];
    const float f0  = fc_w[dir * H_ + j];
    const float f1  = fc_w[2 * H_ + dir * H_ + j];

    float h_j = 0.0f, hnew_prev = 0.0f;
    hrep[0][kq * HREP + j] = 0.0f;

    const bf16* xgb = xg + (size_t)b * T_ * G_;

    // stage window 0
    {
        const size_t tlo = dir ? (size_t)(T_ - WIN) : 0;
        const uint4* src = (const uint4*)(xgb + tlo * G_);
        for (int e = tid; e < WIN * G_ / 8; e += 512) ((uint4*)xgw)[e] = src[e];
    }
    __syncthreads();

    int cur = 0;
    for (int wnd = 0; wnd < T_ / WIN; ++wnd) {
        for (int si = 0; si < WIN; ++si) {
            const int row = dir ? (WIN - 1 - si) : si;
            const float xgr_v = b2f(xgw[row * G_ + j]);
            const float xgz_v = b2f(xgw[row * G_ + H_ + j]);
            const float xgn_v = b2f(xgw[row * G_ + 2 * H_ + j]);

            const float* hp = &hrep[cur][kq * 168];
            float4 hv[8];
            #pragma unroll
            for (int i = 0; i < 8; ++i) hv[i] = *(const float4*)(hp + 4 * i);

            // deferred FC reduce for previous step (overlaps this step's dots)
            if (si > 0) {
                float s0 = (kq == 0) ? f0 * hnew_prev : 0.f;
                float s1 = (kq == 0) ? f1 * hnew_prev : 0.f;
                s0 += __shfl_xor(s0, 4);  s1 += __shfl_xor(s1, 4);
                s0 += __shfl_xor(s0, 8);  s1 += __shfl_xor(s1, 8);
                s0 += __shfl_xor(s0, 16); s1 += __shfl_xor(s1, 16);
                s0 += __shfl_xor(s0, 32); s1 += __shfl_xor(s1, 32);
                if ((tid & 63) == 0) { stash[wid][si - 1][0] = s0; stash[wid][si - 1][1] = s1; }
            }

            float ar = 0.f, az = 0.f, an = 0.f;
            #pragma unroll
            for (int i = 0; i < 8; ++i) {
                const float4 h0 = hv[i];
                ar = fmaf(wr4[i].x, h0.x, ar); ar = fmaf(wr4[i].y, h0.y, ar);
                ar = fmaf(wr4[i].z, h0.z, ar); ar = fmaf(wr4[i].w, h0.w, ar);
                az = fmaf(wz4[i].x, h0.x, az); az = fmaf(wz4[i].y, h0.y, az);
                az = fmaf(wz4[i].z, h0.z, az); az = fmaf(wz4[i].w, h0.w, az);
                an = fmaf(wn4[i].x, h0.x, an); an = fmaf(wn4[i].y, h0.y, an);
                an = fmaf(wn4[i].z, h0.z, an); an = fmaf(wn4[i].w, h0.w, an);
            }
            float sr = ar, sz = az, sh = an;
            sr += __shfl_xor(sr, 1); sr += __shfl_xor(sr, 2);
            sz += __shfl_xor(sz, 1); sz += __shfl_xor(sz, 2);
            sh += __shfl_xor(sh, 1); sh += __shfl_xor(sh, 2);

            const float r = sigf(xgr_v + sr + cr);
            const float z = sigf(xgz_v + sz + cz);
            const float n = tanhf_(xgn_v + r * (sh + cnh));
            const float hnew = n + z * (h_j - n);
            h_j = hnew;
            hrep[cur ^ 1][kq * HREP + j] = hnew;
            cur ^= 1;
            hnew_prev = hnew;
            __syncthreads();
        }

        // FC epilogue for last step of window
        {
            float s0 = (kq == 0) ? f0 * hnew_prev : 0.f;
            float s1 = (kq == 0) ? f1 * hnew_prev : 0.f;
            s0 += __shfl_xor(s0, 4);  s1 += __shfl_xor(s1, 4);
            s0 += __shfl_xor(s0, 8);  s1 += __shfl_xor(s1, 8);
            s0 += __shfl_xor(s0, 16); s1 += __shfl_xor(s1, 16);
            s0 += __shfl_xor(s0, 32); s1 += __shfl_xor(s1, 32);
            if ((tid & 63) == 0) { stash[wid][WIN - 1][0] = s0; stash[wid][WIN - 1][1] = s1; }
        }
        __syncthreads();

        // flush FC results + stage next window
        if (tid < 2 * WIN) {
            const int si = tid >> 1, c = tid & 1;
            const int s = wnd * WIN + si;
            const int t = dir ? (T_ - 1 - s) : s;
            float v = 0.f;
            #pragma unroll
            for (int w = 0; w < 8; ++w) v += stash[w][si][c];
            float* dst = out + ((size_t)b * T_ + t) * 2 + c;
            if (mode == 0)      *dst = fc_b[c] + v;
            else if (mode == 1) *dst = *dst + v;
            else                atomicAdd(dst, v);
        }
        if (wnd + 1 < T_ / WIN) {
            const size_t tlo = dir ? (size_t)(T_ - (wnd + 2) * WIN) : (size_t)(wnd + 1) * WIN;
            const uint4* src = (const uint4*)(xgb + tlo * G_);
            for (int e = tid; e < WIN * G_ / 8; e += 512) ((uint4*)xgw)[e] = src[e];
        }
        __syncthreads();
    }
}

__global__ __launch_bounds__(256) void init_out(float* __restrict__ out,
                                                const float* __restrict__ fcb)
{
    const int i = blockIdx.x * 256 + threadIdx.x;
    out[i] = fcb[i & 1];
}

extern "C" void kernel_launch(void* const* d_in, const int* in_sizes, int n_in,
                              void* d_out, int out_size, void* d_ws, size_t ws_size,
                              hipStream_t stream)
{
    if (n_in < 19) return;
    const float* x     = (const float*)d_in[0];
    const float* wih0  = (const float*)d_in[1];
    const float* whh0  = (const float*)d_in[2];
    const float* bih0  = (const float*)d_in[3];
    const float* bhh0  = (const float*)d_in[4];
    const float* wih0r = (const float*)d_in[5];
    const float* whh0r = (const float*)d_in[6];
    const float* bih0r = (const float*)d_in[7];
    const float* bhh0r = (const float*)d_in[8];
    const float* wih1  = (const float*)d_in[9];
    const float* whh1  = (const float*)d_in[10];
    const float* bih1  = (const float*)d_in[11];
    const float* bhh1  = (const float*)d_in[12];
    const float* wih1r = (const float*)d_in[13];
    const float* whh1r = (const float*)d_in[14];
    const float* bih1r = (const float*)d_in[15];
    const float* bhh1r = (const float*)d_in[16];
    const float* fcw   = (const float*)d_in[17];
    const float* fcb   = (const float*)d_in[18];
    float* out = (float*)d_out;

    const size_t nBT  = (size_t)B_ * T_;
    const size_t l0_b = nBT * 2 * H_ * sizeof(bf16);     // 64 MiB
    const size_t xg_b = nBT * G_ * sizeof(bf16);         // 96 MiB per dir
    const size_t xg_el = nBT * G_;

    if (ws_size < l0_b + xg_b) return;

    bf16* l0o = (bf16*)d_ws;
    bf16* xgf = (bf16*)((char*)d_ws + l0_b);

    gru_l0<<<dim3(2 * B_), dim3(512), 0, stream>>>(
        x, wih0, whh0, bih0, bhh0, wih0r, whh0r, bih0r, bhh0r, l0o);

    if (ws_size >= l0_b + 2 * xg_b) {
        bf16* xgr = xgf + xg_el;
        init_out<<<dim3((B_ * T_ * 2) / 256), dim3(256), 0, stream>>>(out, fcb);
        xg_gemm_mfma<<<dim3(1024, 3), dim3(256), 0, stream>>>(l0o, wih1,  bih1,  xgf);
        xg_gemm_mfma<<<dim3(1024, 3), dim3(256), 0, stream>>>(l0o, wih1r, bih1r, xgr);
        gru_l1<<<dim3(2 * B_), dim3(512), 0, stream>>>(
            xgf, xgr, whh1, bhh1, whh1r, bhh1r, fcw, fcb, out, 2);
    } else {
        xg_gemm_mfma<<<dim3(1024, 3), dim3(256), 0, stream>>>(l0o, wih1, bih1, xgf);
        gru_l1<<<dim3(B_), dim3(512), 0, stream>>>(
            xgf, xgf, whh1, bhh1, whh1r, bhh1r, fcw, fcb, out, 0);
        xg_gemm_mfma<<<dim3(1024, 3), dim3(256), 0, stream>>>(l0o, wih1r, bih1r, xgf);
        gru_l1<<<dim3(B_), dim3(512), 0, stream>>>(
            xgf, xgf, whh1, bhh1, whh1r, bhh1r, fcw, fcb, out, 1);
    }
}